// Round 3
// baseline (503.973 us; speedup 1.0000x reference)
//
#include <hip/hip_runtime.h>
#include <math.h>

// x: (16, 52, 256, 256) fp32, GROUPS=52, cpg=1. One 1024-thread block per
// (b,g) slice; whole 256 KB slice held in registers (16 float4/thread).
// __launch_bounds__(1024,4): 1 block/CU, VGPR cap 128 -> data stays resident
// (round 2 with default bounds got VGPR=64 => compiler re-loaded x 3x).
//
// Index algebra: i = t + 1024k  =>  row = wave + 16k (wave-uniform),
// cols = 4*lane + j (k-invariant). Gaussians collapse to pk[16] (row terms)
// + qj[4] (col terms), computed once, cached in regs.
#define Gn 52
#define HW 65536
#define HW4 16384
#define BG 832
#define TPB 1024
#define VPT 16

__global__ __launch_bounds__(TPB, 4) void k_fused(
    const float4* __restrict__ x4,
    const float* __restrict__ weight, const float* __restrict__ bias,
    const float* __restrict__ one_,  const float* __restrict__ zero,
    const float* __restrict__ theta, const float* __restrict__ scale,
    float4* __restrict__ out4)
{
    const int bg   = blockIdx.x;
    const int g    = bg % Gn;
    const int t    = threadIdx.x;
    const int wave = t >> 6;
    const int lane = t & 63;
    const size_t base4 = (size_t)bg * HW4;
    const float4* xp = x4 + base4;

    // ---- load entire slice into registers ----
    float4 v[VPT];
    #pragma unroll
    for (int k = 0; k < VPT; ++k) v[k] = xp[t + k * TPB];

    // ---- sweep 1: argmax (first occurrence) + sum ----
    float vmax = -INFINITY; int imax = 0; float sum = 0.f;
    #pragma unroll
    for (int k = 0; k < VPT; ++k) {
        int e = (t + k * TPB) * 4;            // increasing in k -> '>' keeps first
        float4 q = v[k];
        sum += (q.x + q.y) + (q.z + q.w);
        if (q.x > vmax) { vmax = q.x; imax = e; }
        if (q.y > vmax) { vmax = q.y; imax = e + 1; }
        if (q.z > vmax) { vmax = q.z; imax = e + 2; }
        if (q.w > vmax) { vmax = q.w; imax = e + 3; }
    }
    #pragma unroll
    for (int off = 32; off > 0; off >>= 1) {
        float ov = __shfl_down(vmax, off);
        int   oi = __shfl_down(imax, off);
        float os = __shfl_down(sum,  off);
        sum += os;
        if (ov > vmax || (ov == vmax && oi < imax)) { vmax = ov; imax = oi; }
    }
    __shared__ float rv[16];
    __shared__ int   ri[16];
    __shared__ float r1[16];
    __shared__ float r2[16];
    __shared__ float bc[6];
    if (lane == 0) { rv[wave] = vmax; ri[wave] = imax; r1[wave] = sum; }
    __syncthreads();
    if (t == 0) {
        float bv = rv[0]; int bi = ri[0]; float bs = r1[0];
        for (int i = 1; i < 16; ++i) {
            bs += r1[i];
            float ov = rv[i]; int oi = ri[i];
            if (ov > bv || (ov == bv && oi < bi)) { bv = ov; bi = oi; }
        }
        bc[0] = bv;                        // qval
        bc[1] = (float)(bi >> 8);          // qrow
        bc[2] = (float)(bi & 255);         // qcol
        bc[3] = bs * (1.f / (float)HW);    // gap
    }
    __syncthreads();

    const float sigma   = scale[0];
    const float inv2s2  = 0.5f / (sigma * sigma);
    const float lognorm = -logf(sigma) - 0.9189385332046727f; // -0.5*log(2pi)
    const float th0 = theta[0], th1 = theta[1];
    const float qrow = bc[1], qcol = bc[2];
    const float Ah = 0.5f * zero[g] * bc[0];   // A/2 (coeff on each gaussian)
    const float Bc = one_[g] * bc[3];          // coeff on x

    // gaussian terms, computed ONCE: pk[k] = Ah*gr(row=wave+16k) + Bc,
    // qj[j] = Ah*gc(col=4*lane+j).  sim = (pk + qj) * x
    float pk[VPT];
    #pragma unroll
    for (int k = 0; k < VPT; ++k) {
        float zr = ((float)(wave + 16 * k) - qrow) * th0;
        pk[k] = Ah * __expf(lognorm - zr * zr * inv2s2) + Bc;
    }
    float qj[4];
    #pragma unroll
    for (int j = 0; j < 4; ++j) {
        float zc = ((float)(4 * lane + j) - qcol) * th1;
        qj[j] = Ah * __expf(lognorm - zc * zc * inv2s2);
    }

    // ---- sweep 2: sim statistics ----
    float s1 = 0.f, s2 = 0.f;
    #pragma unroll
    for (int k = 0; k < VPT; ++k) {
        float4 q = v[k];
        float s;
        s = (pk[k] + qj[0]) * q.x; s1 += s; s2 = fmaf(s, s, s2);
        s = (pk[k] + qj[1]) * q.y; s1 += s; s2 = fmaf(s, s, s2);
        s = (pk[k] + qj[2]) * q.z; s1 += s; s2 = fmaf(s, s, s2);
        s = (pk[k] + qj[3]) * q.w; s1 += s; s2 = fmaf(s, s, s2);
    }
    #pragma unroll
    for (int off = 32; off > 0; off >>= 1) {
        s1 += __shfl_down(s1, off);
        s2 += __shfl_down(s2, off);
    }
    if (lane == 0) { r1[wave] = s1; r2[wave] = s2; }
    __syncthreads();
    if (t == 0) {
        float S1 = 0.f, S2 = 0.f;
        for (int i = 0; i < 16; ++i) { S1 += r1[i]; S2 += r2[i]; }
        float mean = S1 * (1.f / (float)HW);
        float var  = (S2 - S1 * mean) * (1.f / (float)(HW - 1));
        var = fmaxf(var, 0.f);
        bc[4] = mean;
        bc[5] = weight[g] / (sqrtf(var) + 1e-5f);
    }
    __syncthreads();
    const float mean = bc[4], wsc = bc[5];
    const float bb = fmaf(-mean, wsc, bias[g]);   // ctx = sim*wsc + bb

    // ---- sweep 3: gated output ----
    #pragma unroll
    for (int k = 0; k < VPT; ++k) {
        float4 q = v[k], o;
        float s, ctx;
        s = (pk[k] + qj[0]) * q.x; ctx = fmaf(s, wsc, bb);
        o.x = q.x * __builtin_amdgcn_rcpf(1.f + __expf(-ctx));
        s = (pk[k] + qj[1]) * q.y; ctx = fmaf(s, wsc, bb);
        o.y = q.y * __builtin_amdgcn_rcpf(1.f + __expf(-ctx));
        s = (pk[k] + qj[2]) * q.z; ctx = fmaf(s, wsc, bb);
        o.z = q.z * __builtin_amdgcn_rcpf(1.f + __expf(-ctx));
        s = (pk[k] + qj[3]) * q.w; ctx = fmaf(s, wsc, bb);
        o.w = q.w * __builtin_amdgcn_rcpf(1.f + __expf(-ctx));
        out4[base4 + t + k * TPB] = o;
    }
}

extern "C" void kernel_launch(void* const* d_in, const int* in_sizes, int n_in,
                              void* d_out, int out_size, void* d_ws, size_t ws_size,
                              hipStream_t stream) {
    const float* x      = (const float*)d_in[0];
    const float* weight = (const float*)d_in[1];
    const float* bias   = (const float*)d_in[2];
    const float* one_   = (const float*)d_in[3];
    const float* zero   = (const float*)d_in[4];
    const float* theta  = (const float*)d_in[5];
    const float* scale  = (const float*)d_in[6];
    float* out = (float*)d_out;

    k_fused<<<BG, TPB, 0, stream>>>((const float4*)x, weight, bias, one_, zero,
                                    theta, scale, (float4*)out);
}